// Round 5
// baseline (301.929 us; speedup 1.0000x reference)
//
#include <hip/hip_runtime.h>

// TT-chain: N=65536, L=128, D=4, R=8, O=2.
//   m = x[n,0] @ core_first[0]
//   for c in 0..125: m[l] = sum_{k,j} m[k]*cm[c,k,j,l]*x[n,c+1,j]
//   out[n,:] = sum_{k,j} m[k]*cl[k,j,:]*x[n,127,j]
// cm[:, :, 3, :] == I -> j=3 term is x.w*m[l] (exact fp32 path).
//
// R10 design: R9's rolled, I$-resident step loop + fp16-PAIR cores.
//   R9 post-mortem: 2224 cyc/step (model 870): busy 1310 (~3 cyc/instr)
//   + 914 stall. Dominant suspect: 192 v_readlane->v_fma SGPR-RAW hazard
//   pairs per step (VALU SGPR write -> VALU SGPR read wait states) that
//   the scheduler can't separate with only ~50 free SGPRs.
//   Fix: cores packed as fp16 pairs -> 96 readlanes/step (halved), each
//   feeding TWO v_fma_mix_f32 (full-rate fp16 x fp32 -> fp32, SGPR src,
//   op_sel picks the half) -> ~96 fewer issue slots and ~96 fewer hazard
//   windows, plus a natural 1:2 readlane:fma interleave. Chain m[] and
//   the identity j=3 path stay fp32 (same numerics R5/R8 passed with).
//
// Cycle model per SIMD-step: 96 readlane + 192 fma_mix + 32 mul + ~30
// rotate/addr/loop ~ 350 instr x 2 cyc ~ 700 busy + ~250 hazard/loop
// ~ 1000 cyc/step -> ~53 us. HBM: 134 MB over 53 us = 2.5 TB/s < roof.

#define NTHREADS 256

typedef _Float16 h2 __attribute__((ext_vector_type(2)));

// Pack cm[126,8,4,8] (fp32) -> cpk[c*96 + (k*12 + j*4 + u)], fp16 pair
// dword holding (l=2u, l=2u+1), j<3 only. 192-dword zero tail pad (the
// r=1 lane-distributed load overreads 31 dwords past each step slab).
__global__ __launch_bounds__(NTHREADS) void pack_cores_h(
    const float* __restrict__ cm, unsigned int* __restrict__ cpk)
{
    int t = blockIdx.x * NTHREADS + threadIdx.x;
    if (t >= 126 * 96 + 192) return;
    if (t >= 126 * 96) { cpk[t] = 0u; return; }   // pad
    int c = t / 96;
    int d = t % 96;           // k*12 + j*4 + u
    int k = d / 12;
    int r = d % 12;
    int j = r / 4;
    int u = r % 4;
    h2 h;
    h.x = (_Float16)cm[c * 256 + k * 32 + j * 8 + 2 * u + 0];
    h.y = (_Float16)cm[c * 256 + k * 32 + j * 8 + 2 * u + 1];
    cpk[t] = __builtin_bit_cast(unsigned int, h);
}

__global__ __launch_bounds__(NTHREADS, 1) void tt_chain_m(
    const float* __restrict__ x,          // [N,128,4]
    const int* __restrict__ cpk,          // packed fp16-pair cores (+pad)
    const float* __restrict__ cf,         // [1,4,8]
    const float* __restrict__ cl,         // [8,4,2]
    float* __restrict__ out)              // [N,2]
{
    const int tid = threadIdx.x;
    const int n = blockIdx.x * NTHREADS + tid;   // grid covers N exactly
    const int ln = tid & 63;                     // hardware lane

    const float4* __restrict__ xr = reinterpret_cast<const float4*>(x) + (size_t)n * 128;

    // ---- prologue ----
    const float4 x0 = xr[0];

    // core staging: step s = 96 dwords, lane-distributed over 2 VGPRs:
    // dword d of step s lives in reg (d>>6), lane (d&63), loaded from
    // cpk[s*96 + r*64 + ln]  (r=1 overreads 31 dwords -> pad/next step)
    int vC[2], vN[2];
    #pragma unroll
    for (int r = 0; r < 2; ++r) vC[r] = cpk[r * 64 + ln];          // step 0
    #pragma unroll
    for (int r = 0; r < 2; ++r) vN[r] = cpk[96 + r * 64 + ln];     // step 1

    // x pipeline: xc = row(c+1) (consumed by step c), +2 rows in flight
    float4 xc  = xr[1];
    float4 xn1 = xr[2];
    float4 xn2 = xr[3];

    float m[8];
    #pragma unroll
    for (int k = 0; k < 8; ++k)
        m[k] = fmaf(cf[k], x0.x,
               fmaf(cf[8 + k], x0.y,
               fmaf(cf[16 + k], x0.z, cf[24 + k] * x0.w)));

    // ---- rolled step loop: c = 0..125 (I$-resident body) ----
    #pragma unroll 1
    for (int c = 0; c < 126; ++c) {
        float nm[8];
        #pragma unroll
        for (int l = 0; l < 8; ++l) nm[l] = xc.w * m[l];   // j=3 identity
        #pragma unroll
        for (int k = 0; k < 8; ++k) {
            const float p0 = m[k] * xc.x;
            const float p1 = m[k] * xc.y;
            const float p2 = m[k] * xc.z;
            #pragma unroll
            for (int j = 0; j < 3; ++j) {
                const float pj = (j == 0) ? p0 : (j == 1) ? p1 : p2;
                #pragma unroll
                for (int u = 0; u < 4; ++u) {
                    const int d = k * 12 + j * 4 + u;      // compile-time
                    const int sv = __builtin_amdgcn_readlane(vC[d >> 6], d & 63);
                    const h2 h = __builtin_bit_cast(h2, sv);
                    nm[2 * u + 0] = fmaf((float)h.x, pj, nm[2 * u + 0]);
                    nm[2 * u + 1] = fmaf((float)h.y, pj, nm[2 * u + 1]);
                }
            }
        }
        #pragma unroll
        for (int l = 0; l < 8; ++l) m[l] = nm[l];

        // rotate pipelines, then issue next prefetches
        vC[0] = vN[0]; vC[1] = vN[1];
        xc = xn1; xn1 = xn2;

        const int cn = (c + 2 < 126) ? c + 2 : 125;        // core step c+2
        #pragma unroll
        for (int r = 0; r < 2; ++r) vN[r] = cpk[cn * 96 + r * 64 + ln];
        const int tx = (c + 4 < 128) ? c + 4 : 127;        // x row c+4
        xn2 = xr[tx];
    }

    // ---- epilogue: xc = row 127 after final rotation ----
    {
        const float xj[4] = { xc.x, xc.y, xc.z, xc.w };
        float o0 = 0.f, o1 = 0.f;
        #pragma unroll
        for (int j = 0; j < 4; ++j) {
            float v0 = 0.f, v1 = 0.f;
            #pragma unroll
            for (int k = 0; k < 8; ++k) {
                v0 = fmaf(m[k], cl[k * 8 + j * 2 + 0], v0);
                v1 = fmaf(m[k], cl[k * 8 + j * 2 + 1], v1);
            }
            o0 = fmaf(xj[j], v0, o0);
            o1 = fmaf(xj[j], v1, o1);
        }
        reinterpret_cast<float2*>(out)[n] = make_float2(o0, o1);
    }
}

extern "C" void kernel_launch(void* const* d_in, const int* in_sizes, int n_in,
                              void* d_out, int out_size, void* d_ws, size_t ws_size,
                              hipStream_t stream) {
    const float* x  = (const float*)d_in[0];   // [N,128,4]
    const float* cf = (const float*)d_in[1];   // [1,4,8]
    const float* cm = (const float*)d_in[2];   // [126,8,4,8]
    const float* cl = (const float*)d_in[3];   // [8,4,2]
    float* out = (float*)d_out;                // [N,2]

    const int N = in_sizes[0] / (128 * 4);

    // packed fp16-pair cores: (126*96 + 192) dwords = 49152 B in workspace
    unsigned int* cpk = (unsigned int*)d_ws;

    pack_cores_h<<<(126 * 96 + 192 + NTHREADS - 1) / NTHREADS, NTHREADS, 0, stream>>>(cm, cpk);

    tt_chain_m<<<N / NTHREADS, NTHREADS, 0, stream>>>(x, (const int*)cpk, cf, cl, out);
}